// Round 1
// baseline (476.934 us; speedup 1.0000x reference)
//
#include <hip/hip_runtime.h>

#define KNBR 32

// ---------------- Pass 1: sum of X (for mean) ----------------
__global__ void __launch_bounds__(256) sum_kernel(const float* __restrict__ X, int n,
                                                  double* __restrict__ sum) {
    double local = 0.0;
    int stride = gridDim.x * blockDim.x;
    int n4 = n >> 2;  // n = 1M, divisible by 4
    const float4* X4 = (const float4*)X;
    for (int i = blockIdx.x * blockDim.x + threadIdx.x; i < n4; i += stride) {
        float4 v = X4[i];
        local += (double)v.x + (double)v.y + (double)v.z + (double)v.w;
    }
    // tail (n not multiple of 4)
    for (int i = (n4 << 2) + blockIdx.x * blockDim.x + threadIdx.x; i < n; i += stride)
        local += (double)X[i];

    // wave (64-lane) reduction
    for (int off = 32; off; off >>= 1)
        local += __shfl_down(local, off, 64);

    __shared__ double lds[4];
    int lane = threadIdx.x & 63;
    int wid  = threadIdx.x >> 6;
    if (lane == 0) lds[wid] = local;
    __syncthreads();
    if (threadIdx.x == 0) {
        double b = lds[0] + lds[1] + lds[2] + lds[3];
        atomicAdd(sum, b);  // f64 global atomic, device scope
    }
}

// ---------------- Pass 2: local Moran per row ----------------
// One lane per (row, j) pair: j = lane & 31, two rows per 64-lane wave.
// W/IDS reads are fully coalesced; X gathers hit L2/L3 (X is only 4 MB).
__global__ void __launch_bounds__(256) moran_kernel(const float* __restrict__ X,
                                                    const float* __restrict__ W,
                                                    const int*   __restrict__ IDS,
                                                    const double* __restrict__ sumptr,
                                                    float* __restrict__ out, int n) {
    int gid = blockIdx.x * blockDim.x + threadIdx.x;  // item over n*K (32M < 2^31)
    float mean = (float)(*sumptr * (1.0 / (double)n));
    if (gid >= n * KNBR) return;

    float w  = W[gid];
    int   id = IDS[gid];
    float xn  = X[id] - mean;
    float wxn = w * xn;
    float lag = wxn;
    float s2  = wxn * xn;  // w * xn^2

    // reduce across the 32-lane half-wave
    #pragma unroll
    for (int off = 16; off; off >>= 1) {
        lag += __shfl_down(lag, off, 32);
        s2  += __shfl_down(s2,  off, 32);
    }

    if ((threadIdx.x & 31) == 0) {
        int row = gid >> 5;
        float xa = X[row] - mean;
        out[row] = xa * lag * (float)(KNBR - 1) / s2;
    }
}

extern "C" void kernel_launch(void* const* d_in, const int* in_sizes, int n_in,
                              void* d_out, int out_size, void* d_ws, size_t ws_size,
                              hipStream_t stream) {
    const float* X   = (const float*)d_in[0];
    const float* W   = (const float*)d_in[1];
    const int*   IDS = (const int*)d_in[2];
    float* out = (float*)d_out;
    int n = in_sizes[0];

    double* sum = (double*)d_ws;
    hipMemsetAsync(d_ws, 0, sizeof(double), stream);  // ws is re-poisoned 0xAA every call

    sum_kernel<<<1024, 256, 0, stream>>>(X, n, sum);

    int total = n * KNBR;
    int blocks = (total + 255) / 256;
    moran_kernel<<<blocks, 256, 0, stream>>>(X, W, IDS, sum, out, n);
}